// Round 10
// baseline (4065.327 us; speedup 1.0000x reference)
//
#include <hip/hip_runtime.h>

#define BATCH 16
#define NPTS  2048
#define NMAT  32   // 16 batches x 2 preds
#define ITERS 20

typedef short bf16x8 __attribute__((ext_vector_type(8)));
typedef float f32x4 __attribute__((ext_vector_type(4)));
typedef unsigned short ushort_t;
typedef unsigned int uint_t;

// K = log2(e)/EPS, EPS = 0.05. Potentials pre-scaled: F = f*K (log2-domain).
// No LSE shift needed: terms 2^(pv - K*C) stay in fp32 range by ~80 bits.
constexpr float KSCALE = 28.853900817779268f;

__device__ __forceinline__ float fexp2(float x){ return __builtin_amdgcn_exp2f(x); }
__device__ __forceinline__ float flog2(float x){ return __builtin_amdgcn_logf(x); }
__device__ __forceinline__ float fsqrt_(float x){ return __builtin_amdgcn_sqrtf(x); }

__device__ __forceinline__ ushort_t bfr16(float x){
  uint_t u = __float_as_uint(x);
  return (ushort_t)((u + 0x7FFFu + ((u >> 16) & 1u)) >> 16);
}
__device__ __forceinline__ float bfrf(float x){
  return __uint_as_float(((uint_t)bfr16(x)) << 16);
}

// Per-point MFMA fragment encodings (27 used slots of K=32), bf16:
// per component c: L=[nh,nm,nl, 1,1,1, -2ah,-2ah,-2al], R=[1,1,1, nh,nm,nl, bh,bl,bh]
// sum_k L_k(p)*R_k(g) = |p|^2 + |g|^2 - 2(ah*bh+ah*bl+al*bh) ~= ||p-g||^2.
// Storage per cloud: 128 tiles x 1KB; lane l of tile t reads 16B at t*1024+l*16.
__device__ __forceinline__ void store_enc(ushort_t* base, int pt, const ushort_t* enc){
  ushort_t* p = base + (pt >> 4) * 512 + (pt & 15) * 8;
#pragma unroll
  for (int g = 0; g < 4; ++g){
    *reinterpret_cast<ushort4*>(p + g*128)     = make_ushort4(enc[g*8+0],enc[g*8+1],enc[g*8+2],enc[g*8+3]);
    *reinterpret_cast<ushort4*>(p + g*128 + 4) = make_ushort4(enc[g*8+4],enc[g*8+5],enc[g*8+6],enc[g*8+7]);
  }
}

__global__ void __launch_bounds__(256) pack_kernel(
    const float* __restrict__ gt, const float* __restrict__ p0, const float* __restrict__ p1,
    ushort_t* __restrict__ Lpred, ushort_t* __restrict__ Rpred,
    ushort_t* __restrict__ Lgt,   ushort_t* __restrict__ Rgt,
    float* __restrict__ emd, float* __restrict__ chamf, uint_t* __restrict__ mbar)
{
  const int idx = blockIdx.x * 256 + threadIdx.x;
  const int totalPts = (NMAT + BATCH) * NPTS;
  if (idx < totalPts) {
    const int cl = idx >> 11, pt = idx & (NPTS - 1);
    const float* src; ushort_t *Lb, *Rb;
    if (cl < NMAT) {
      const int b = cl >> 1;
      src = ((cl & 1) ? p1 : p0) + (b * NPTS + pt) * 3;
      Lb = Lpred + cl * 65536; Rb = Rpred + cl * 65536;
    } else {
      const int b = cl - NMAT;
      src = gt + (b * NPTS + pt) * 3;
      Lb = Lgt + b * 65536; Rb = Rgt + b * 65536;
    }
    float L[32], R[32];
#pragma unroll
    for (int k = 27; k < 32; ++k){ L[k] = 0.f; R[k] = 0.f; }
#pragma unroll
    for (int c = 0; c < 3; ++c){
      const float v  = src[c];
      const float ah = bfrf(v), al = bfrf(v - ah);
      const float n2 = v * v;
      const float nh = bfrf(n2); const float r1 = n2 - nh;
      const float nm = bfrf(r1); const float nl = bfrf(r1 - nm);
      const int B0 = c * 9;
      L[B0+0]=nh;  L[B0+1]=nm;  L[B0+2]=nl;
      L[B0+3]=1.f; L[B0+4]=1.f; L[B0+5]=1.f;
      L[B0+6]=-2.f*ah; L[B0+7]=-2.f*ah; L[B0+8]=-2.f*al;
      R[B0+0]=1.f; R[B0+1]=1.f; R[B0+2]=1.f;
      R[B0+3]=nh;  R[B0+4]=nm;  R[B0+5]=nl;
      R[B0+6]=ah;  R[B0+7]=al;  R[B0+8]=ah;
    }
    ushort_t Le[32], Re[32];
#pragma unroll
    for (int k = 0; k < 32; ++k){ Le[k] = bfr16(L[k]); Re[k] = bfr16(R[k]); }
    store_enc(Lb, pt, Le);
    store_enc(Rb, pt, Re);
  } else if (idx == totalPts) {
    emd[0] = 0.f;
  } else if (idx == totalPts + 1) {
    chamf[0] = 0.f;
  } else if (idx < totalPts + 2 + NMAT) {
    mbar[idx - totalPts - 2] = 0u;   // per-matrix barrier counters
  }
}

// One Sinkhorn half-update body (64 rows x 2048 cols per block, 8 waves =
// 4 row-waves x 2 col-halves). Potentials in group-of-4 layout:
// pot[(t>>2)*64 + c*4 + (t&3)] for point i = t*16+c.
template<int CHAM, int COST>
__device__ __forceinline__ void phase_body(
    float (&ssum)[8][16], float (&sdm)[8][16], float (&sds)[4],
    const bf16x8 af, const ushort_t* __restrict__ Bu,
    const float* __restrict__ PTu, const int rpot,
    const int l, const int w, const int rg5,
    float* __restrict__ poutT, float* __restrict__ chamf, float* __restrict__ emd)
{
  const int tid = threadIdx.x;
  float s0=0.f,s1=0.f,s2=0.f,s3=0.f;
  float d0=1e30f,d1=1e30f,d2=1e30f,d3=1e30f;
  float t0=0.f,t1=0.f,t2=0.f,t3=0.f;
  const f32x4 zz = {0.f,0.f,0.f,0.f};
  const int voff = l * 8;

  auto tilef = [&](const bf16x8& bfr, float pv) {
    f32x4 d4 = __builtin_amdgcn_mfma_f32_16x16x32_bf16(af, bfr, zz, 0, 0, 0);
    const float da=fmaxf(d4[0],1e-12f), db=fmaxf(d4[1],1e-12f);
    const float dc=fmaxf(d4[2],1e-12f), dd=fmaxf(d4[3],1e-12f);
    if (CHAM){ d0=fminf(d0,da); d1=fminf(d1,db); d2=fminf(d2,dc); d3=fminf(d3,dd); }
    const float Ca=fsqrt_(da), Cb=fsqrt_(db), Cc=fsqrt_(dc), Cd=fsqrt_(dd);
    const float xa=fexp2(fmaf(-KSCALE,Ca,pv)), xb=fexp2(fmaf(-KSCALE,Cb,pv));
    const float xc=fexp2(fmaf(-KSCALE,Cc,pv)), xd=fexp2(fmaf(-KSCALE,Cd,pv));
    s0+=xa; s1+=xb; s2+=xc; s3+=xd;
    if (COST){
      t0=fmaf(xa,Ca,t0); t1=fmaf(xb,Cb,t1);
      t2=fmaf(xc,Cc,t2); t3=fmaf(xd,Cd,t3);
    }
  };

#pragma unroll 2
  for (int g4 = 0; g4 < 16; ++g4) {
    const ushort_t* Bg = Bu + g4 * 2048;
    float4 cp;
    if (rpot) cp = *reinterpret_cast<const float4*>(PTu + g4*64);
    else      cp = make_float4(0.f,0.f,0.f,0.f);
    tilef(*reinterpret_cast<const bf16x8*>(Bg + voff +    0), cp.x);
    tilef(*reinterpret_cast<const bf16x8*>(Bg + voff +  512), cp.y);
    tilef(*reinterpret_cast<const bf16x8*>(Bg + voff + 1024), cp.z);
    tilef(*reinterpret_cast<const bf16x8*>(Bg + voff + 1536), cp.w);
  }

#pragma unroll
  for (int o = 1; o < 16; o <<= 1) {
    s0 += __shfl_xor(s0,o); s1 += __shfl_xor(s1,o);
    s2 += __shfl_xor(s2,o); s3 += __shfl_xor(s3,o);
    if (CHAM){
      d0=fminf(d0,__shfl_xor(d0,o)); d1=fminf(d1,__shfl_xor(d1,o));
      d2=fminf(d2,__shfl_xor(d2,o)); d3=fminf(d3,__shfl_xor(d3,o));
    }
    if (COST){
      t0 += __shfl_xor(t0,o); t1 += __shfl_xor(t1,o);
      t2 += __shfl_xor(t2,o); t3 += __shfl_xor(t3,o);
    }
  }
  if ((l & 15) == 0) {
    const int g = l >> 4;
    ssum[w][g*4+0]=s0; ssum[w][g*4+1]=s1; ssum[w][g*4+2]=s2; ssum[w][g*4+3]=s3;
    if (CHAM){ sdm[w][g*4+0]=d0; sdm[w][g*4+1]=d1; sdm[w][g*4+2]=d2; sdm[w][g*4+3]=d3; }
    if (COST){ sdm[w][g*4+0]=t0; sdm[w][g*4+1]=t1; sdm[w][g*4+2]=t2; sdm[w][g*4+3]=t3; }
  }
  __syncthreads();
  float val = 0.f;
  if (w < 4 && l < 16) {
    const float S = ssum[w][l] + ssum[w+4][l];
    val = -11.0f - flog2(S);
    poutT[rg5*64 + l*4 + w] = val;   // dense 256B per block
  }
  if (CHAM) {
    if (w < 4) {
      float dmr = (l < 16) ? fminf(sdm[w][l], sdm[w+4][l]) : 0.f;
#pragma unroll
      for (int o = 1; o < 16; o <<= 1) dmr += __shfl_xor(dmr, o);
      if (l == 0) sds[w] = dmr;
    }
    __syncthreads();
    if (tid == 0) atomicAdd(chamf, (sds[0]+sds[1])+(sds[2]+sds[3]));
  }
  if (COST) {
    if (w < 4) {
      float cj = (l < 16) ? fexp2(val) * (sdm[w][l] + sdm[w+4][l]) : 0.f;
#pragma unroll
      for (int o = 1; o < 16; o <<= 1) cj += __shfl_xor(cj, o);
      if (l == 0) sds[w] = cj;
    }
    __syncthreads();
    if (tid == 0) atomicAdd(emd, (sds[0]+sds[1])+(sds[2]+sds[3]));
  }
}

// Cooperative mega-kernel: all 40 half-updates in one dispatch.
// XCD swizzle keeps each matrix's 32 blocks on one XCD; phases are separated
// by a per-matrix monotonic-counter barrier (cheap, mostly XCD-local).
__global__ void __launch_bounds__(512, 8) mega_kernel(
    const ushort_t* __restrict__ Lpred, const ushort_t* __restrict__ Rpred,
    const ushort_t* __restrict__ Lgt,   const ushort_t* __restrict__ Rgt,
    float* __restrict__ FT, float* __restrict__ GT,
    float* __restrict__ chamf, float* __restrict__ emd, uint_t* __restrict__ mbar)
{
  __shared__ float ssum[8][16], sdm[8][16], sds[4];
  const int bx0 = blockIdx.x;
  const int bx  = (bx0 & 7) * (NMAT * 32 / 8) + (bx0 >> 3);
  const int m = bx >> 5, rg5 = bx & 31, b = m >> 1;
  const int tid = threadIdx.x, l = tid & 63;
  const int w = __builtin_amdgcn_readfirstlane(tid >> 6);
  const int wr = w & 3, half = w >> 2;
  const int myrow16 = rg5*64 + wr*16;

  const bf16x8 af0 = *reinterpret_cast<const bf16x8*>(Lpred + m*65536 + (myrow16>>4)*512 + l*8);
  const bf16x8 af1 = *reinterpret_cast<const bf16x8*>(Lgt   + b*65536 + (myrow16>>4)*512 + l*8);
  const ushort_t* Bu0 = Rgt   + b*65536 + half*32768;
  const ushort_t* Bu1 = Rpred + m*65536 + half*32768;
  float* FTm = FT + m*NPTS;
  float* GTm = GT + m*NPTS;
  const int ptoff = half*1024 + (l & 15)*4;

  uint_t target = 0;
  for (int ph = 0; ph < 2*ITERS; ++ph) {
    const int gside = ph & 1;
    const bf16x8 af = gside ? af1 : af0;
    const ushort_t* Bu = gside ? Bu1 : Bu0;
    const float* PTu = (gside ? FTm : GTm) + ptoff;
    float* poutT = gside ? GTm : FTm;

    if (ph == 0)
      phase_body<1,0>(ssum,sdm,sds, af,Bu,PTu,0, l,w,rg5, poutT, chamf, emd);
    else if (ph == 1)
      phase_body<1,0>(ssum,sdm,sds, af,Bu,PTu,1, l,w,rg5, poutT, chamf, emd);
    else if (ph == 2*ITERS-1)
      phase_body<0,1>(ssum,sdm,sds, af,Bu,PTu,1, l,w,rg5, poutT, chamf, emd);
    else
      phase_body<0,0>(ssum,sdm,sds, af,Bu,PTu,1, l,w,rg5, poutT, chamf, emd);

    if (ph < 2*ITERS-1) {
      __syncthreads();             // all potential stores issued & drained
      target += 32;
      if (tid == 0) {
        __threadfence();           // release: make stores agent-visible
        __hip_atomic_fetch_add(&mbar[m], 1u, __ATOMIC_RELAXED, __HIP_MEMORY_SCOPE_AGENT);
        while (__hip_atomic_load(&mbar[m], __ATOMIC_RELAXED, __HIP_MEMORY_SCOPE_AGENT) < target)
          __builtin_amdgcn_s_sleep(2);
        __threadfence();           // acquire: invalidate caches before reads
      }
      __syncthreads();
    }
  }
}

// Fallback path (round-9 proven): one dispatch per half-update.
template<int CHAM, int RPOT, int GSIDE, int COST>
__global__ void __launch_bounds__(512, 8) sink_kernel(
    const ushort_t* __restrict__ Lpred, const ushort_t* __restrict__ Rpred,
    const ushort_t* __restrict__ Lgt,   const ushort_t* __restrict__ Rgt,
    float* __restrict__ FT, float* __restrict__ GT,
    float* __restrict__ chamf, float* __restrict__ emd)
{
  __shared__ float ssum[8][16], sdm[8][16], sds[4];
  const int bx0 = blockIdx.x;
  const int bx  = (bx0 & 7) * (NMAT * 32 / 8) + (bx0 >> 3);
  const int m = bx >> 5, rg5 = bx & 31, b = m >> 1;
  const int tid = threadIdx.x, l = tid & 63;
  const int w = __builtin_amdgcn_readfirstlane(tid >> 6);
  const int wr = w & 3, half = w >> 2;
  const int myrow16 = rg5*64 + wr*16;
  const ushort_t* A  = GSIDE ? (Lgt + b*65536) : (Lpred + m*65536);
  const ushort_t* Bu = (GSIDE ? (Rpred + m*65536) : (Rgt + b*65536)) + half*32768;
  const float* PTu = ((GSIDE ? FT : GT) + m*NPTS) + half*1024 + (l&15)*4;
  float* poutT = (GSIDE ? GT : FT) + m*NPTS;
  const bf16x8 af = *reinterpret_cast<const bf16x8*>(A + (myrow16>>4)*512 + l*8);
  phase_body<CHAM,COST>(ssum,sdm,sds, af,Bu,PTu,RPOT, l,w,rg5, poutT, chamf, emd);
}

__global__ void final_kernel(const float* __restrict__ emd,
                             const float* __restrict__ chamf,
                             float* __restrict__ out)
{
  if (blockIdx.x == 0 && threadIdx.x == 0) {
    out[0] = chamf[0] / (float)(BATCH * NPTS) + emd[0] / (float)BATCH;
  }
}

extern "C" void kernel_launch(void* const* d_in, const int* in_sizes, int n_in,
                              void* d_out, int out_size, void* d_ws, size_t ws_size,
                              hipStream_t stream) {
  (void)in_sizes; (void)n_in; (void)out_size; (void)ws_size;
  const float* gt = (const float*)d_in[0];
  const float* p0 = (const float*)d_in[2];
  const float* p1 = (const float*)d_in[3];

  ushort_t* Lpred = (ushort_t*)d_ws;                  // 4MB
  ushort_t* Rpred = Lpred + NMAT * 65536;             // 4MB
  ushort_t* Lgt   = Rpred + NMAT * 65536;             // 2MB
  ushort_t* Rgt   = Lgt + BATCH * 65536;              // 2MB
  float* FT    = (float*)(Rgt + BATCH * 65536);       // 32*2048 (grouped-T)
  float* GT    = FT + NMAT * NPTS;                    // 32*2048 (grouped-T)
  float* emd   = GT + NMAT * NPTS;                    // 1
  float* chamf = emd + 1;                             // 1
  uint_t* mbar = (uint_t*)(chamf + 1);                // 32

  const int initN = (NMAT + BATCH) * NPTS + 2 + NMAT;
  pack_kernel<<<(initN + 255) / 256, 256, 0, stream>>>(
      gt, p0, p1, Lpred, Rpred, Lgt, Rgt, emd, chamf, mbar);

  const int grid = NMAT * 32;   // 1024 blocks = exactly 4/CU at 8 waves/SIMD

  void* args[] = {(void*)&Lpred, (void*)&Rpred, (void*)&Lgt, (void*)&Rgt,
                  (void*)&FT, (void*)&GT, (void*)&chamf, (void*)&emd, (void*)&mbar};
  hipError_t ce = hipLaunchCooperativeKernel(
      reinterpret_cast<void*>(&mega_kernel), dim3(grid), dim3(512), args, 0, stream);
  if (ce != hipSuccess) {
    (void)hipGetLastError();   // clear sticky error; use classic path
    sink_kernel<1, 0, 0, 0><<<grid, 512, 0, stream>>>(Lpred, Rpred, Lgt, Rgt, FT, GT, chamf, emd);
    sink_kernel<1, 1, 1, 0><<<grid, 512, 0, stream>>>(Lpred, Rpred, Lgt, Rgt, FT, GT, chamf, emd);
    for (int it = 1; it < ITERS - 1; ++it) {
      sink_kernel<0, 1, 0, 0><<<grid, 512, 0, stream>>>(Lpred, Rpred, Lgt, Rgt, FT, GT, chamf, emd);
      sink_kernel<0, 1, 1, 0><<<grid, 512, 0, stream>>>(Lpred, Rpred, Lgt, Rgt, FT, GT, chamf, emd);
    }
    sink_kernel<0, 1, 0, 0><<<grid, 512, 0, stream>>>(Lpred, Rpred, Lgt, Rgt, FT, GT, chamf, emd);
    sink_kernel<0, 1, 1, 1><<<grid, 512, 0, stream>>>(Lpred, Rpred, Lgt, Rgt, FT, GT, chamf, emd);
  }

  final_kernel<<<1, 64, 0, stream>>>(emd, chamf, (float*)d_out);
}

// Round 11
// 2334.015 us; speedup vs baseline: 1.7418x; 1.7418x over previous
//
#include <hip/hip_runtime.h>

#define BATCH 16
#define NPTS  2048
#define NMAT  32   // 16 batches x 2 preds
#define ITERS 20

typedef short bf16x8 __attribute__((ext_vector_type(8)));
typedef float f32x4 __attribute__((ext_vector_type(4)));
typedef unsigned short ushort_t;
typedef unsigned int uint_t;
typedef unsigned long long u64_t;

// K = log2(e)/EPS, EPS = 0.05. Potentials pre-scaled: F = f*K (log2-domain).
// No LSE shift needed: terms 2^(pv - K*C) stay in fp32 range by ~80 bits.
constexpr float KSCALE = 28.853900817779268f;

__device__ __forceinline__ float fexp2(float x){ return __builtin_amdgcn_exp2f(x); }
__device__ __forceinline__ float flog2(float x){ return __builtin_amdgcn_logf(x); }
__device__ __forceinline__ float fsqrt_(float x){ return __builtin_amdgcn_sqrtf(x); }

__device__ __forceinline__ ushort_t bfr16(float x){
  uint_t u = __float_as_uint(x);
  return (ushort_t)((u + 0x7FFFu + ((u >> 16) & 1u)) >> 16);
}
__device__ __forceinline__ float bfrf(float x){
  return __uint_as_float(((uint_t)bfr16(x)) << 16);
}

// Per-point MFMA fragment encodings (27 used slots of K=32), bf16:
// per component c: L=[nh,nm,nl, 1,1,1, -2ah,-2ah,-2al], R=[1,1,1, nh,nm,nl, bh,bl,bh]
// sum_k L_k(p)*R_k(g) = |p|^2 + |g|^2 - 2(ah*bh+ah*bl+al*bh) ~= ||p-g||^2.
// Storage per cloud: 128 tiles x 1KB; lane l of tile t reads 16B at t*1024+l*16.
__device__ __forceinline__ void store_enc(ushort_t* base, int pt, const ushort_t* enc){
  ushort_t* p = base + (pt >> 4) * 512 + (pt & 15) * 8;
#pragma unroll
  for (int g = 0; g < 4; ++g){
    *reinterpret_cast<ushort4*>(p + g*128)     = make_ushort4(enc[g*8+0],enc[g*8+1],enc[g*8+2],enc[g*8+3]);
    *reinterpret_cast<ushort4*>(p + g*128 + 4) = make_ushort4(enc[g*8+4],enc[g*8+5],enc[g*8+6],enc[g*8+7]);
  }
}

__global__ void __launch_bounds__(256) pack_kernel(
    const float* __restrict__ gt, const float* __restrict__ p0, const float* __restrict__ p1,
    ushort_t* __restrict__ Lpred, ushort_t* __restrict__ Rpred,
    ushort_t* __restrict__ Lgt,   ushort_t* __restrict__ Rgt,
    float* __restrict__ emd, float* __restrict__ chamf, uint_t* __restrict__ mbar)
{
  const int idx = blockIdx.x * 256 + threadIdx.x;
  const int totalPts = (NMAT + BATCH) * NPTS;
  if (idx < totalPts) {
    const int cl = idx >> 11, pt = idx & (NPTS - 1);
    const float* src; ushort_t *Lb, *Rb;
    if (cl < NMAT) {
      const int b = cl >> 1;
      src = ((cl & 1) ? p1 : p0) + (b * NPTS + pt) * 3;
      Lb = Lpred + cl * 65536; Rb = Rpred + cl * 65536;
    } else {
      const int b = cl - NMAT;
      src = gt + (b * NPTS + pt) * 3;
      Lb = Lgt + b * 65536; Rb = Rgt + b * 65536;
    }
    float L[32], R[32];
#pragma unroll
    for (int k = 27; k < 32; ++k){ L[k] = 0.f; R[k] = 0.f; }
#pragma unroll
    for (int c = 0; c < 3; ++c){
      const float v  = src[c];
      const float ah = bfrf(v), al = bfrf(v - ah);
      const float n2 = v * v;
      const float nh = bfrf(n2); const float r1 = n2 - nh;
      const float nm = bfrf(r1); const float nl = bfrf(r1 - nm);
      const int B0 = c * 9;
      L[B0+0]=nh;  L[B0+1]=nm;  L[B0+2]=nl;
      L[B0+3]=1.f; L[B0+4]=1.f; L[B0+5]=1.f;
      L[B0+6]=-2.f*ah; L[B0+7]=-2.f*ah; L[B0+8]=-2.f*al;
      R[B0+0]=1.f; R[B0+1]=1.f; R[B0+2]=1.f;
      R[B0+3]=nh;  R[B0+4]=nm;  R[B0+5]=nl;
      R[B0+6]=ah;  R[B0+7]=al;  R[B0+8]=ah;
    }
    ushort_t Le[32], Re[32];
#pragma unroll
    for (int k = 0; k < 32; ++k){ Le[k] = bfr16(L[k]); Re[k] = bfr16(R[k]); }
    store_enc(Lb, pt, Le);
    store_enc(Rb, pt, Re);
  } else if (idx == totalPts) {
    emd[0] = 0.f;
  } else if (idx == totalPts + 1) {
    chamf[0] = 0.f;
  } else if (idx < totalPts + 2 + NMAT) {
    mbar[idx - totalPts - 2] = 0u;   // per-matrix barrier counters
  }
}

// One Sinkhorn half-update body (64 rows x 2048 cols per block, 8 waves =
// 4 row-waves x 2 col-halves). Potentials in group-of-4 layout:
// pot[(t>>2)*64 + c*4 + (t&3)] for point i = t*16+c.
// Potential reads: coherent (agent-scope atomic) 8B loads staged into LDS.
// Potential writes: coherent (agent-scope atomic) stores.
template<int CHAM, int COST>
__device__ __forceinline__ void phase_body(
    float (&ssum)[8][16], float (&sdm)[8][16], float (&sds)[4], float (&spot)[2048],
    const bf16x8 af, const ushort_t* __restrict__ Bu,
    const float* __restrict__ pinT, const int rpot,
    const int l, const int w, const int half, const int rg5,
    float* __restrict__ poutT, float* __restrict__ chamf, float* __restrict__ emd)
{
  const int tid = threadIdx.x;

  if (rpot) {
    // stage all 2048 col-potentials coherently (bypass stale L1/L2) into LDS
    const u64_t* Ps = reinterpret_cast<const u64_t*>(pinT);
    u64_t v0 = __hip_atomic_load(Ps + tid,       __ATOMIC_RELAXED, __HIP_MEMORY_SCOPE_AGENT);
    u64_t v1 = __hip_atomic_load(Ps + 512 + tid, __ATOMIC_RELAXED, __HIP_MEMORY_SCOPE_AGENT);
    *reinterpret_cast<u64_t*>(&spot[tid*2])        = v0;
    *reinterpret_cast<u64_t*>(&spot[1024 + tid*2]) = v1;
    __syncthreads();
  }

  float s0=0.f,s1=0.f,s2=0.f,s3=0.f;
  float d0=1e30f,d1=1e30f,d2=1e30f,d3=1e30f;
  float t0=0.f,t1=0.f,t2=0.f,t3=0.f;
  const f32x4 zz = {0.f,0.f,0.f,0.f};
  const int voff = l * 8;
  const float* sp = &spot[half*1024 + (l & 15)*4];

  auto tilef = [&](const bf16x8& bfr, float pv) {
    f32x4 d4 = __builtin_amdgcn_mfma_f32_16x16x32_bf16(af, bfr, zz, 0, 0, 0);
    const float da=fmaxf(d4[0],1e-12f), db=fmaxf(d4[1],1e-12f);
    const float dc=fmaxf(d4[2],1e-12f), dd=fmaxf(d4[3],1e-12f);
    if (CHAM){ d0=fminf(d0,da); d1=fminf(d1,db); d2=fminf(d2,dc); d3=fminf(d3,dd); }
    const float Ca=fsqrt_(da), Cb=fsqrt_(db), Cc=fsqrt_(dc), Cd=fsqrt_(dd);
    const float xa=fexp2(fmaf(-KSCALE,Ca,pv)), xb=fexp2(fmaf(-KSCALE,Cb,pv));
    const float xc=fexp2(fmaf(-KSCALE,Cc,pv)), xd=fexp2(fmaf(-KSCALE,Cd,pv));
    s0+=xa; s1+=xb; s2+=xc; s3+=xd;
    if (COST){
      t0=fmaf(xa,Ca,t0); t1=fmaf(xb,Cb,t1);
      t2=fmaf(xc,Cc,t2); t3=fmaf(xd,Cd,t3);
    }
  };

#pragma unroll 2
  for (int g4 = 0; g4 < 16; ++g4) {
    const ushort_t* Bg = Bu + g4 * 2048;
    float4 cp;
    if (rpot) cp = *reinterpret_cast<const float4*>(sp + g4*64);
    else      cp = make_float4(0.f,0.f,0.f,0.f);
    tilef(*reinterpret_cast<const bf16x8*>(Bg + voff +    0), cp.x);
    tilef(*reinterpret_cast<const bf16x8*>(Bg + voff +  512), cp.y);
    tilef(*reinterpret_cast<const bf16x8*>(Bg + voff + 1024), cp.z);
    tilef(*reinterpret_cast<const bf16x8*>(Bg + voff + 1536), cp.w);
  }

#pragma unroll
  for (int o = 1; o < 16; o <<= 1) {
    s0 += __shfl_xor(s0,o); s1 += __shfl_xor(s1,o);
    s2 += __shfl_xor(s2,o); s3 += __shfl_xor(s3,o);
    if (CHAM){
      d0=fminf(d0,__shfl_xor(d0,o)); d1=fminf(d1,__shfl_xor(d1,o));
      d2=fminf(d2,__shfl_xor(d2,o)); d3=fminf(d3,__shfl_xor(d3,o));
    }
    if (COST){
      t0 += __shfl_xor(t0,o); t1 += __shfl_xor(t1,o);
      t2 += __shfl_xor(t2,o); t3 += __shfl_xor(t3,o);
    }
  }
  if ((l & 15) == 0) {
    const int g = l >> 4;
    ssum[w][g*4+0]=s0; ssum[w][g*4+1]=s1; ssum[w][g*4+2]=s2; ssum[w][g*4+3]=s3;
    if (CHAM){ sdm[w][g*4+0]=d0; sdm[w][g*4+1]=d1; sdm[w][g*4+2]=d2; sdm[w][g*4+3]=d3; }
    if (COST){ sdm[w][g*4+0]=t0; sdm[w][g*4+1]=t1; sdm[w][g*4+2]=t2; sdm[w][g*4+3]=t3; }
  }
  __syncthreads();
  float val = 0.f;
  if (w < 4 && l < 16) {
    const float S = ssum[w][l] + ssum[w+4][l];
    val = -11.0f - flog2(S);
    __hip_atomic_store(&poutT[rg5*64 + l*4 + w], val,
                       __ATOMIC_RELAXED, __HIP_MEMORY_SCOPE_AGENT);
  }
  if (CHAM) {
    if (w < 4) {
      float dmr = (l < 16) ? fminf(sdm[w][l], sdm[w+4][l]) : 0.f;
#pragma unroll
      for (int o = 1; o < 16; o <<= 1) dmr += __shfl_xor(dmr, o);
      if (l == 0) sds[w] = dmr;
    }
    __syncthreads();
    if (tid == 0) atomicAdd(chamf, (sds[0]+sds[1])+(sds[2]+sds[3]));
  }
  if (COST) {
    if (w < 4) {
      float cj = (l < 16) ? fexp2(val) * (sdm[w][l] + sdm[w+4][l]) : 0.f;
#pragma unroll
      for (int o = 1; o < 16; o <<= 1) cj += __shfl_xor(cj, o);
      if (l == 0) sds[w] = cj;
    }
    __syncthreads();
    if (tid == 0) atomicAdd(emd, (sds[0]+sds[1])+(sds[2]+sds[3]));
  }
}

// Cooperative mega-kernel: all 40 half-updates in one dispatch.
// Per-matrix 32-block barrier: RELAXED agent atomics only — NO __threadfence
// (agent fences trigger full L2 wb/inv on multi-XCD gfx950; the only shared
// data, the potentials, are exchanged via per-access coherent atomics, and
// __syncthreads' vmcnt(0) drain orders the stores before the counter bump).
__global__ void __launch_bounds__(512, 8) mega_kernel(
    const ushort_t* __restrict__ Lpred, const ushort_t* __restrict__ Rpred,
    const ushort_t* __restrict__ Lgt,   const ushort_t* __restrict__ Rgt,
    float* __restrict__ FT, float* __restrict__ GT,
    float* __restrict__ chamf, float* __restrict__ emd, uint_t* __restrict__ mbar)
{
  __shared__ float ssum[8][16], sdm[8][16], sds[4];
  __shared__ float spot[2048];
  const int bx0 = blockIdx.x;
  const int bx  = (bx0 & 7) * (NMAT * 32 / 8) + (bx0 >> 3);  // XCD-contiguous
  const int m = bx >> 5, rg5 = bx & 31, b = m >> 1;
  const int tid = threadIdx.x, l = tid & 63;
  const int w = __builtin_amdgcn_readfirstlane(tid >> 6);
  const int wr = w & 3, half = w >> 2;
  const int myrow16 = rg5*64 + wr*16;

  const bf16x8 af0 = *reinterpret_cast<const bf16x8*>(Lpred + m*65536 + (myrow16>>4)*512 + l*8);
  const bf16x8 af1 = *reinterpret_cast<const bf16x8*>(Lgt   + b*65536 + (myrow16>>4)*512 + l*8);
  const ushort_t* Bu0 = Rgt   + b*65536 + half*32768;
  const ushort_t* Bu1 = Rpred + m*65536 + half*32768;
  float* FTm = FT + m*NPTS;
  float* GTm = GT + m*NPTS;

  for (int ph = 0; ph < 2*ITERS; ++ph) {
    const int gside = ph & 1;
    const bf16x8 af = gside ? af1 : af0;
    const ushort_t* Bu = gside ? Bu1 : Bu0;
    const float* pinT = gside ? FTm : GTm;
    float* poutT = gside ? GTm : FTm;

    if (ph == 0)
      phase_body<1,0>(ssum,sdm,sds,spot, af,Bu,pinT,0, l,w,half,rg5, poutT, chamf, emd);
    else if (ph == 1)
      phase_body<1,0>(ssum,sdm,sds,spot, af,Bu,pinT,1, l,w,half,rg5, poutT, chamf, emd);
    else if (ph == 2*ITERS-1)
      phase_body<0,1>(ssum,sdm,sds,spot, af,Bu,pinT,1, l,w,half,rg5, poutT, chamf, emd);
    else
      phase_body<0,0>(ssum,sdm,sds,spot, af,Bu,pinT,1, l,w,half,rg5, poutT, chamf, emd);

    if (ph < 2*ITERS-1) {
      __syncthreads();   // drains vmcnt: coherent potential stores are visible
      if (tid == 0) {
        __hip_atomic_fetch_add(&mbar[m], 1u, __ATOMIC_RELAXED, __HIP_MEMORY_SCOPE_AGENT);
        const uint_t tgt = 32u * (uint_t)(ph + 1);
        while (__hip_atomic_load(&mbar[m], __ATOMIC_RELAXED, __HIP_MEMORY_SCOPE_AGENT) < tgt)
          __builtin_amdgcn_s_sleep(1);
      }
      __syncthreads();
    }
  }
}

// Fallback path (round-9 proven): one dispatch per half-update.
template<int CHAM, int RPOT, int GSIDE, int COST>
__global__ void __launch_bounds__(512, 8) sink_kernel(
    const ushort_t* __restrict__ Lpred, const ushort_t* __restrict__ Rpred,
    const ushort_t* __restrict__ Lgt,   const ushort_t* __restrict__ Rgt,
    float* __restrict__ FT, float* __restrict__ GT,
    float* __restrict__ chamf, float* __restrict__ emd)
{
  __shared__ float ssum[8][16], sdm[8][16], sds[4];
  __shared__ float spot[2048];
  const int bx0 = blockIdx.x;
  const int bx  = (bx0 & 7) * (NMAT * 32 / 8) + (bx0 >> 3);
  const int m = bx >> 5, rg5 = bx & 31, b = m >> 1;
  const int tid = threadIdx.x, l = tid & 63;
  const int w = __builtin_amdgcn_readfirstlane(tid >> 6);
  const int wr = w & 3, half = w >> 2;
  const int myrow16 = rg5*64 + wr*16;
  const ushort_t* A  = GSIDE ? (Lgt + b*65536) : (Lpred + m*65536);
  const ushort_t* Bu = (GSIDE ? (Rpred + m*65536) : (Rgt + b*65536)) + half*32768;
  const float* pinT = (GSIDE ? FT : GT) + m*NPTS;
  float* poutT = (GSIDE ? GT : FT) + m*NPTS;
  const bf16x8 af = *reinterpret_cast<const bf16x8*>(A + (myrow16>>4)*512 + l*8);
  phase_body<CHAM,COST>(ssum,sdm,sds,spot, af,Bu,pinT,RPOT, l,w,half,rg5, poutT, chamf, emd);
}

__global__ void final_kernel(const float* __restrict__ emd,
                             const float* __restrict__ chamf,
                             float* __restrict__ out)
{
  if (blockIdx.x == 0 && threadIdx.x == 0) {
    out[0] = chamf[0] / (float)(BATCH * NPTS) + emd[0] / (float)BATCH;
  }
}

extern "C" void kernel_launch(void* const* d_in, const int* in_sizes, int n_in,
                              void* d_out, int out_size, void* d_ws, size_t ws_size,
                              hipStream_t stream) {
  (void)in_sizes; (void)n_in; (void)out_size; (void)ws_size;
  const float* gt = (const float*)d_in[0];
  const float* p0 = (const float*)d_in[2];
  const float* p1 = (const float*)d_in[3];

  ushort_t* Lpred = (ushort_t*)d_ws;                  // 4MB
  ushort_t* Rpred = Lpred + NMAT * 65536;             // 4MB
  ushort_t* Lgt   = Rpred + NMAT * 65536;             // 2MB
  ushort_t* Rgt   = Lgt + BATCH * 65536;              // 2MB
  float* FT    = (float*)(Rgt + BATCH * 65536);       // 32*2048 (grouped-T)
  float* GT    = FT + NMAT * NPTS;                    // 32*2048 (grouped-T)
  float* emd   = GT + NMAT * NPTS;                    // 1
  float* chamf = emd + 1;                             // 1
  uint_t* mbar = (uint_t*)(chamf + 1);                // 32

  const int initN = (NMAT + BATCH) * NPTS + 2 + NMAT;
  pack_kernel<<<(initN + 255) / 256, 256, 0, stream>>>(
      gt, p0, p1, Lpred, Rpred, Lgt, Rgt, emd, chamf, mbar);

  const int grid = NMAT * 32;   // 1024 blocks = exactly 4/CU at 8 waves/SIMD

  void* args[] = {(void*)&Lpred, (void*)&Rpred, (void*)&Lgt, (void*)&Rgt,
                  (void*)&FT, (void*)&GT, (void*)&chamf, (void*)&emd, (void*)&mbar};
  hipError_t ce = hipLaunchCooperativeKernel(
      reinterpret_cast<void*>(&mega_kernel), dim3(grid), dim3(512), args, 0, stream);
  if (ce != hipSuccess) {
    (void)hipGetLastError();   // clear sticky error; use classic path
    sink_kernel<1, 0, 0, 0><<<grid, 512, 0, stream>>>(Lpred, Rpred, Lgt, Rgt, FT, GT, chamf, emd);
    sink_kernel<1, 1, 1, 0><<<grid, 512, 0, stream>>>(Lpred, Rpred, Lgt, Rgt, FT, GT, chamf, emd);
    for (int it = 1; it < ITERS - 1; ++it) {
      sink_kernel<0, 1, 0, 0><<<grid, 512, 0, stream>>>(Lpred, Rpred, Lgt, Rgt, FT, GT, chamf, emd);
      sink_kernel<0, 1, 1, 0><<<grid, 512, 0, stream>>>(Lpred, Rpred, Lgt, Rgt, FT, GT, chamf, emd);
    }
    sink_kernel<0, 1, 0, 0><<<grid, 512, 0, stream>>>(Lpred, Rpred, Lgt, Rgt, FT, GT, chamf, emd);
    sink_kernel<0, 1, 1, 1><<<grid, 512, 0, stream>>>(Lpred, Rpred, Lgt, Rgt, FT, GT, chamf, emd);
  }

  final_kernel<<<1, 64, 0, stream>>>(emd, chamf, (float*)d_out);
}

// Round 12
// 1623.718 us; speedup vs baseline: 2.5037x; 1.4375x over previous
//
#include <hip/hip_runtime.h>

#define BATCH 16
#define NPTS  2048
#define NMAT  32   // 16 batches x 2 preds
#define ITERS 20
#define MBAR_STRIDE 32   // pad each matrix's barrier counter to its own 128B line

typedef short bf16x8 __attribute__((ext_vector_type(8)));
typedef float f32x4 __attribute__((ext_vector_type(4)));
typedef unsigned short ushort_t;
typedef unsigned int uint_t;
typedef unsigned long long u64_t;

// K = log2(e)/EPS, EPS = 0.05. Potentials pre-scaled: F = f*K (log2-domain).
// No LSE shift needed: terms 2^(pv - K*C) stay in fp32 range by ~80 bits.
constexpr float KSCALE = 28.853900817779268f;

__device__ __forceinline__ float fexp2(float x){ return __builtin_amdgcn_exp2f(x); }
__device__ __forceinline__ float flog2(float x){ return __builtin_amdgcn_logf(x); }
__device__ __forceinline__ float fsqrt_(float x){ return __builtin_amdgcn_sqrtf(x); }

__device__ __forceinline__ ushort_t bfr16(float x){
  uint_t u = __float_as_uint(x);
  return (ushort_t)((u + 0x7FFFu + ((u >> 16) & 1u)) >> 16);
}
__device__ __forceinline__ float bfrf(float x){
  return __uint_as_float(((uint_t)bfr16(x)) << 16);
}

// Per-point MFMA fragment encodings (27 used slots of K=32), bf16:
// per component c: L=[nh,nm,nl, 1,1,1, -2ah,-2ah,-2al], R=[1,1,1, nh,nm,nl, bh,bl,bh]
// sum_k L_k(p)*R_k(g) = |p|^2 + |g|^2 - 2(ah*bh+ah*bl+al*bh) ~= ||p-g||^2.
// Storage per cloud: 128 tiles x 1KB; lane l of tile t reads 16B at t*1024+l*16.
__device__ __forceinline__ void store_enc(ushort_t* base, int pt, const ushort_t* enc){
  ushort_t* p = base + (pt >> 4) * 512 + (pt & 15) * 8;
#pragma unroll
  for (int g = 0; g < 4; ++g){
    *reinterpret_cast<ushort4*>(p + g*128)     = make_ushort4(enc[g*8+0],enc[g*8+1],enc[g*8+2],enc[g*8+3]);
    *reinterpret_cast<ushort4*>(p + g*128 + 4) = make_ushort4(enc[g*8+4],enc[g*8+5],enc[g*8+6],enc[g*8+7]);
  }
}

__global__ void __launch_bounds__(256) pack_kernel(
    const float* __restrict__ gt, const float* __restrict__ p0, const float* __restrict__ p1,
    ushort_t* __restrict__ Lpred, ushort_t* __restrict__ Rpred,
    ushort_t* __restrict__ Lgt,   ushort_t* __restrict__ Rgt,
    float* __restrict__ emd, float* __restrict__ chamf, uint_t* __restrict__ mbar)
{
  const int idx = blockIdx.x * 256 + threadIdx.x;
  const int totalPts = (NMAT + BATCH) * NPTS;
  if (idx < totalPts) {
    const int cl = idx >> 11, pt = idx & (NPTS - 1);
    const float* src; ushort_t *Lb, *Rb;
    if (cl < NMAT) {
      const int b = cl >> 1;
      src = ((cl & 1) ? p1 : p0) + (b * NPTS + pt) * 3;
      Lb = Lpred + cl * 65536; Rb = Rpred + cl * 65536;
    } else {
      const int b = cl - NMAT;
      src = gt + (b * NPTS + pt) * 3;
      Lb = Lgt + b * 65536; Rb = Rgt + b * 65536;
    }
    float L[32], R[32];
#pragma unroll
    for (int k = 27; k < 32; ++k){ L[k] = 0.f; R[k] = 0.f; }
#pragma unroll
    for (int c = 0; c < 3; ++c){
      const float v  = src[c];
      const float ah = bfrf(v), al = bfrf(v - ah);
      const float n2 = v * v;
      const float nh = bfrf(n2); const float r1 = n2 - nh;
      const float nm = bfrf(r1); const float nl = bfrf(r1 - nm);
      const int B0 = c * 9;
      L[B0+0]=nh;  L[B0+1]=nm;  L[B0+2]=nl;
      L[B0+3]=1.f; L[B0+4]=1.f; L[B0+5]=1.f;
      L[B0+6]=-2.f*ah; L[B0+7]=-2.f*ah; L[B0+8]=-2.f*al;
      R[B0+0]=1.f; R[B0+1]=1.f; R[B0+2]=1.f;
      R[B0+3]=nh;  R[B0+4]=nm;  R[B0+5]=nl;
      R[B0+6]=ah;  R[B0+7]=al;  R[B0+8]=ah;
    }
    ushort_t Le[32], Re[32];
#pragma unroll
    for (int k = 0; k < 32; ++k){ Le[k] = bfr16(L[k]); Re[k] = bfr16(R[k]); }
    store_enc(Lb, pt, Le);
    store_enc(Rb, pt, Re);
  } else if (idx == totalPts) {
    emd[0] = 0.f;
  } else if (idx == totalPts + 1) {
    chamf[0] = 0.f;
  } else if (idx < totalPts + 2 + NMAT * MBAR_STRIDE) {
    mbar[idx - totalPts - 2] = 0u;   // padded per-matrix barrier counters
  }
}

// One Sinkhorn half-update body (64 rows x 2048 cols per block, 8 waves =
// 4 row-waves x 2 col-halves). Potentials in group-of-4 layout:
// pot[(t>>2)*64 + c*4 + (t&3)] for point i = t*16+c.
// Potential reads: coherent (agent-scope atomic) 8B loads staged into LDS.
// Potential writes: coherent (agent-scope atomic) stores.
template<int CHAM, int COST>
__device__ __forceinline__ void phase_body(
    float (&ssum)[8][16], float (&sdm)[8][16], float (&sds)[4], float (&spot)[2048],
    const bf16x8 af, const ushort_t* __restrict__ Bu,
    const float* __restrict__ pinT, const int rpot,
    const int l, const int w, const int half, const int rg5,
    float* __restrict__ poutT, float* __restrict__ chamf, float* __restrict__ emd)
{
  const int tid = threadIdx.x;

  if (rpot) {
    // stage all 2048 col-potentials coherently (bypass stale L1/L2) into LDS
    const u64_t* Ps = reinterpret_cast<const u64_t*>(pinT);
    u64_t v0 = __hip_atomic_load(Ps + tid,       __ATOMIC_RELAXED, __HIP_MEMORY_SCOPE_AGENT);
    u64_t v1 = __hip_atomic_load(Ps + 512 + tid, __ATOMIC_RELAXED, __HIP_MEMORY_SCOPE_AGENT);
    *reinterpret_cast<u64_t*>(&spot[tid*2])        = v0;
    *reinterpret_cast<u64_t*>(&spot[1024 + tid*2]) = v1;
    __syncthreads();
  }

  float s0=0.f,s1=0.f,s2=0.f,s3=0.f;
  float d0=1e30f,d1=1e30f,d2=1e30f,d3=1e30f;
  float t0=0.f,t1=0.f,t2=0.f,t3=0.f;
  const f32x4 zz = {0.f,0.f,0.f,0.f};
  const int voff = l * 8;
  const float* sp = &spot[half*1024 + (l & 15)*4];

  auto tilef = [&](const bf16x8& bfr, float pv) {
    f32x4 d4 = __builtin_amdgcn_mfma_f32_16x16x32_bf16(af, bfr, zz, 0, 0, 0);
    const float da=fmaxf(d4[0],1e-12f), db=fmaxf(d4[1],1e-12f);
    const float dc=fmaxf(d4[2],1e-12f), dd=fmaxf(d4[3],1e-12f);
    if (CHAM){ d0=fminf(d0,da); d1=fminf(d1,db); d2=fminf(d2,dc); d3=fminf(d3,dd); }
    const float Ca=fsqrt_(da), Cb=fsqrt_(db), Cc=fsqrt_(dc), Cd=fsqrt_(dd);
    const float xa=fexp2(fmaf(-KSCALE,Ca,pv)), xb=fexp2(fmaf(-KSCALE,Cb,pv));
    const float xc=fexp2(fmaf(-KSCALE,Cc,pv)), xd=fexp2(fmaf(-KSCALE,Cd,pv));
    s0+=xa; s1+=xb; s2+=xc; s3+=xd;
    if (COST){
      t0=fmaf(xa,Ca,t0); t1=fmaf(xb,Cb,t1);
      t2=fmaf(xc,Cc,t2); t3=fmaf(xd,Cd,t3);
    }
  };

#pragma unroll 2
  for (int g4 = 0; g4 < 16; ++g4) {
    const ushort_t* Bg = Bu + g4 * 2048;
    float4 cp;
    if (rpot) cp = *reinterpret_cast<const float4*>(sp + g4*64);
    else      cp = make_float4(0.f,0.f,0.f,0.f);
    tilef(*reinterpret_cast<const bf16x8*>(Bg + voff +    0), cp.x);
    tilef(*reinterpret_cast<const bf16x8*>(Bg + voff +  512), cp.y);
    tilef(*reinterpret_cast<const bf16x8*>(Bg + voff + 1024), cp.z);
    tilef(*reinterpret_cast<const bf16x8*>(Bg + voff + 1536), cp.w);
  }

#pragma unroll
  for (int o = 1; o < 16; o <<= 1) {
    s0 += __shfl_xor(s0,o); s1 += __shfl_xor(s1,o);
    s2 += __shfl_xor(s2,o); s3 += __shfl_xor(s3,o);
    if (CHAM){
      d0=fminf(d0,__shfl_xor(d0,o)); d1=fminf(d1,__shfl_xor(d1,o));
      d2=fminf(d2,__shfl_xor(d2,o)); d3=fminf(d3,__shfl_xor(d3,o));
    }
    if (COST){
      t0 += __shfl_xor(t0,o); t1 += __shfl_xor(t1,o);
      t2 += __shfl_xor(t2,o); t3 += __shfl_xor(t3,o);
    }
  }
  if ((l & 15) == 0) {
    const int g = l >> 4;
    ssum[w][g*4+0]=s0; ssum[w][g*4+1]=s1; ssum[w][g*4+2]=s2; ssum[w][g*4+3]=s3;
    if (CHAM){ sdm[w][g*4+0]=d0; sdm[w][g*4+1]=d1; sdm[w][g*4+2]=d2; sdm[w][g*4+3]=d3; }
    if (COST){ sdm[w][g*4+0]=t0; sdm[w][g*4+1]=t1; sdm[w][g*4+2]=t2; sdm[w][g*4+3]=t3; }
  }
  __syncthreads();
  float val = 0.f;
  if (w < 4 && l < 16) {
    const float S = ssum[w][l] + ssum[w+4][l];
    val = -11.0f - flog2(S);
    __hip_atomic_store(&poutT[rg5*64 + l*4 + w], val,
                       __ATOMIC_RELAXED, __HIP_MEMORY_SCOPE_AGENT);
  }
  if (CHAM) {
    if (w < 4) {
      float dmr = (l < 16) ? fminf(sdm[w][l], sdm[w+4][l]) : 0.f;
#pragma unroll
      for (int o = 1; o < 16; o <<= 1) dmr += __shfl_xor(dmr, o);
      if (l == 0) sds[w] = dmr;
    }
    __syncthreads();
    if (tid == 0) atomicAdd(chamf, (sds[0]+sds[1])+(sds[2]+sds[3]));
  }
  if (COST) {
    if (w < 4) {
      float cj = (l < 16) ? fexp2(val) * (sdm[w][l] + sdm[w+4][l]) : 0.f;
#pragma unroll
      for (int o = 1; o < 16; o <<= 1) cj += __shfl_xor(cj, o);
      if (l == 0) sds[w] = cj;
    }
    __syncthreads();
    if (tid == 0) atomicAdd(emd, (sds[0]+sds[1])+(sds[2]+sds[3]));
  }
}

// Cooperative mega-kernel: all 40 half-updates in one dispatch.
// Per-matrix 32-block barrier: RELAXED agent atomics, one 128B line per
// matrix (no false sharing), s_sleep(32) backoff (~0.85us) so probe traffic
// is trivial. No __threadfence (it would force full L2 wb/inv per phase);
// the shared potentials travel via per-access coherent atomics and the
// vmcnt(0) drain in __syncthreads orders stores before the counter bump.
__global__ void __launch_bounds__(512, 8) mega_kernel(
    const ushort_t* __restrict__ Lpred, const ushort_t* __restrict__ Rpred,
    const ushort_t* __restrict__ Lgt,   const ushort_t* __restrict__ Rgt,
    float* __restrict__ FT, float* __restrict__ GT,
    float* __restrict__ chamf, float* __restrict__ emd, uint_t* __restrict__ mbar)
{
  __shared__ float ssum[8][16], sdm[8][16], sds[4];
  __shared__ float spot[2048];
  const int bx0 = blockIdx.x;
  const int bx  = (bx0 & 7) * (NMAT * 32 / 8) + (bx0 >> 3);  // XCD-contiguous
  const int m = bx >> 5, rg5 = bx & 31, b = m >> 1;
  const int tid = threadIdx.x, l = tid & 63;
  const int w = __builtin_amdgcn_readfirstlane(tid >> 6);
  const int wr = w & 3, half = w >> 2;
  const int myrow16 = rg5*64 + wr*16;

  const bf16x8 af0 = *reinterpret_cast<const bf16x8*>(Lpred + m*65536 + (myrow16>>4)*512 + l*8);
  const bf16x8 af1 = *reinterpret_cast<const bf16x8*>(Lgt   + b*65536 + (myrow16>>4)*512 + l*8);
  const ushort_t* Bu0 = Rgt   + b*65536 + half*32768;
  const ushort_t* Bu1 = Rpred + m*65536 + half*32768;
  float* FTm = FT + m*NPTS;
  float* GTm = GT + m*NPTS;
  uint_t* bar = &mbar[m * MBAR_STRIDE];

  for (int ph = 0; ph < 2*ITERS; ++ph) {
    const int gside = ph & 1;
    const bf16x8 af = gside ? af1 : af0;
    const ushort_t* Bu = gside ? Bu1 : Bu0;
    const float* pinT = gside ? FTm : GTm;
    float* poutT = gside ? GTm : FTm;

    if (ph == 0)
      phase_body<1,0>(ssum,sdm,sds,spot, af,Bu,pinT,0, l,w,half,rg5, poutT, chamf, emd);
    else if (ph == 1)
      phase_body<1,0>(ssum,sdm,sds,spot, af,Bu,pinT,1, l,w,half,rg5, poutT, chamf, emd);
    else if (ph == 2*ITERS-1)
      phase_body<0,1>(ssum,sdm,sds,spot, af,Bu,pinT,1, l,w,half,rg5, poutT, chamf, emd);
    else
      phase_body<0,0>(ssum,sdm,sds,spot, af,Bu,pinT,1, l,w,half,rg5, poutT, chamf, emd);

    if (ph < 2*ITERS-1) {
      __syncthreads();   // drains vmcnt: coherent potential stores are visible
      if (tid == 0) {
        __hip_atomic_fetch_add(bar, 1u, __ATOMIC_RELAXED, __HIP_MEMORY_SCOPE_AGENT);
        const uint_t tgt = 32u * (uint_t)(ph + 1);
        while (__hip_atomic_load(bar, __ATOMIC_RELAXED, __HIP_MEMORY_SCOPE_AGENT) < tgt)
          __builtin_amdgcn_s_sleep(32);   // ~0.85us backoff: no LLC hot-spot
      }
      __syncthreads();
    }
  }
}

// Fallback path (round-9 proven): one dispatch per half-update.
template<int CHAM, int RPOT, int GSIDE, int COST>
__global__ void __launch_bounds__(512, 8) sink_kernel(
    const ushort_t* __restrict__ Lpred, const ushort_t* __restrict__ Rpred,
    const ushort_t* __restrict__ Lgt,   const ushort_t* __restrict__ Rgt,
    float* __restrict__ FT, float* __restrict__ GT,
    float* __restrict__ chamf, float* __restrict__ emd)
{
  __shared__ float ssum[8][16], sdm[8][16], sds[4];
  __shared__ float spot[2048];
  const int bx0 = blockIdx.x;
  const int bx  = (bx0 & 7) * (NMAT * 32 / 8) + (bx0 >> 3);
  const int m = bx >> 5, rg5 = bx & 31, b = m >> 1;
  const int tid = threadIdx.x, l = tid & 63;
  const int w = __builtin_amdgcn_readfirstlane(tid >> 6);
  const int wr = w & 3, half = w >> 2;
  const int myrow16 = rg5*64 + wr*16;
  const ushort_t* A  = GSIDE ? (Lgt + b*65536) : (Lpred + m*65536);
  const ushort_t* Bu = (GSIDE ? (Rpred + m*65536) : (Rgt + b*65536)) + half*32768;
  const float* pinT = (GSIDE ? FT : GT) + m*NPTS;
  float* poutT = (GSIDE ? GT : FT) + m*NPTS;
  const bf16x8 af = *reinterpret_cast<const bf16x8*>(A + (myrow16>>4)*512 + l*8);
  phase_body<CHAM,COST>(ssum,sdm,sds,spot, af,Bu,pinT,RPOT, l,w,half,rg5, poutT, chamf, emd);
}

__global__ void final_kernel(const float* __restrict__ emd,
                             const float* __restrict__ chamf,
                             float* __restrict__ out)
{
  if (blockIdx.x == 0 && threadIdx.x == 0) {
    out[0] = chamf[0] / (float)(BATCH * NPTS) + emd[0] / (float)BATCH;
  }
}

extern "C" void kernel_launch(void* const* d_in, const int* in_sizes, int n_in,
                              void* d_out, int out_size, void* d_ws, size_t ws_size,
                              hipStream_t stream) {
  (void)in_sizes; (void)n_in; (void)out_size; (void)ws_size;
  const float* gt = (const float*)d_in[0];
  const float* p0 = (const float*)d_in[2];
  const float* p1 = (const float*)d_in[3];

  ushort_t* Lpred = (ushort_t*)d_ws;                  // 4MB
  ushort_t* Rpred = Lpred + NMAT * 65536;             // 4MB
  ushort_t* Lgt   = Rpred + NMAT * 65536;             // 2MB
  ushort_t* Rgt   = Lgt + BATCH * 65536;              // 2MB
  float* FT    = (float*)(Rgt + BATCH * 65536);       // 32*2048 (grouped-T)
  float* GT    = FT + NMAT * NPTS;                    // 32*2048 (grouped-T)
  float* emd   = GT + NMAT * NPTS;                    // 1
  float* chamf = emd + 1;                             // 1
  uint_t* mbar = (uint_t*)(chamf + 1);                // 32 * 32 (padded lines)

  const int initN = (NMAT + BATCH) * NPTS + 2 + NMAT * MBAR_STRIDE;
  pack_kernel<<<(initN + 255) / 256, 256, 0, stream>>>(
      gt, p0, p1, Lpred, Rpred, Lgt, Rgt, emd, chamf, mbar);

  const int grid = NMAT * 32;   // 1024 blocks = exactly 4/CU at 8 waves/SIMD

  void* args[] = {(void*)&Lpred, (void*)&Rpred, (void*)&Lgt, (void*)&Rgt,
                  (void*)&FT, (void*)&GT, (void*)&chamf, (void*)&emd, (void*)&mbar};
  hipError_t ce = hipLaunchCooperativeKernel(
      reinterpret_cast<void*>(&mega_kernel), dim3(grid), dim3(512), args, 0, stream);
  if (ce != hipSuccess) {
    (void)hipGetLastError();   // clear sticky error; use classic path
    sink_kernel<1, 0, 0, 0><<<grid, 512, 0, stream>>>(Lpred, Rpred, Lgt, Rgt, FT, GT, chamf, emd);
    sink_kernel<1, 1, 1, 0><<<grid, 512, 0, stream>>>(Lpred, Rpred, Lgt, Rgt, FT, GT, chamf, emd);
    for (int it = 1; it < ITERS - 1; ++it) {
      sink_kernel<0, 1, 0, 0><<<grid, 512, 0, stream>>>(Lpred, Rpred, Lgt, Rgt, FT, GT, chamf, emd);
      sink_kernel<0, 1, 1, 0><<<grid, 512, 0, stream>>>(Lpred, Rpred, Lgt, Rgt, FT, GT, chamf, emd);
    }
    sink_kernel<0, 1, 0, 0><<<grid, 512, 0, stream>>>(Lpred, Rpred, Lgt, Rgt, FT, GT, chamf, emd);
    sink_kernel<0, 1, 1, 1><<<grid, 512, 0, stream>>>(Lpred, Rpred, Lgt, Rgt, FT, GT, chamf, emd);
  }

  final_kernel<<<1, 64, 0, stream>>>(emd, chamf, (float*)d_out);
}

// Round 13
// 1145.647 us; speedup vs baseline: 3.5485x; 1.4173x over previous
//
#include <hip/hip_runtime.h>

#define BATCH 16
#define NPTS  2048
#define NMAT  32   // 16 batches x 2 preds
#define ITERS 20

typedef short bf16x8 __attribute__((ext_vector_type(8)));
typedef float f32x4 __attribute__((ext_vector_type(4)));
typedef unsigned short ushort_t;
typedef unsigned int uint_t;

// K = log2(e)/EPS, EPS = 0.05. Potentials pre-scaled: F = f*K (log2-domain).
// No LSE shift needed: terms 2^(pv - K*C) stay in fp32 range by ~80 bits.
constexpr float KSCALE = 28.853900817779268f;

__device__ __forceinline__ float fexp2(float x){ return __builtin_amdgcn_exp2f(x); }
__device__ __forceinline__ float flog2(float x){ return __builtin_amdgcn_logf(x); }
// sqrt(|x|): abs folds into v_sqrt_f32 as a free input modifier (no clamp needed;
// MFMA d is positive for all real pairs in this data, |error| ~1e-4 max).
__device__ __forceinline__ float fsqrta(float x){ return __builtin_amdgcn_sqrtf(__builtin_fabsf(x)); }

__device__ __forceinline__ ushort_t bfr16(float x){
  uint_t u = __float_as_uint(x);
  return (ushort_t)((u + 0x7FFFu + ((u >> 16) & 1u)) >> 16);
}
__device__ __forceinline__ float bfrf(float x){
  return __uint_as_float(((uint_t)bfr16(x)) << 16);
}

// Per-point MFMA fragment encodings (27 used slots of K=32), bf16:
// per component c: L=[nh,nm,nl, 1,1,1, -2ah,-2ah,-2al], R=[1,1,1, nh,nm,nl, bh,bl,bh]
// sum_k L_k(p)*R_k(g) = |p|^2 + |g|^2 - 2(ah*bh+ah*bl+al*bh) ~= ||p-g||^2.
// Storage per cloud: 128 tiles x 1KB; lane l of tile t reads 16B at t*1024+l*16
// holding point (l&15)'s slots (l>>4)*8..+7 (A and B identical layout).
__device__ __forceinline__ void store_enc(ushort_t* base, int pt, const ushort_t* enc){
  ushort_t* p = base + (pt >> 4) * 512 + (pt & 15) * 8;
#pragma unroll
  for (int g = 0; g < 4; ++g){
    *reinterpret_cast<ushort4*>(p + g*128)     = make_ushort4(enc[g*8+0],enc[g*8+1],enc[g*8+2],enc[g*8+3]);
    *reinterpret_cast<ushort4*>(p + g*128 + 4) = make_ushort4(enc[g*8+4],enc[g*8+5],enc[g*8+6],enc[g*8+7]);
  }
}

__global__ void __launch_bounds__(256) pack_kernel(
    const float* __restrict__ gt, const float* __restrict__ p0, const float* __restrict__ p1,
    ushort_t* __restrict__ Lpred, ushort_t* __restrict__ Rpred,
    ushort_t* __restrict__ Lgt,   ushort_t* __restrict__ Rgt,
    float* __restrict__ emd, float* __restrict__ chamf)
{
  const int idx = blockIdx.x * 256 + threadIdx.x;
  const int totalPts = (NMAT + BATCH) * NPTS;
  if (idx < totalPts) {
    const int cl = idx >> 11, pt = idx & (NPTS - 1);
    const float* src; ushort_t *Lb, *Rb;
    if (cl < NMAT) {
      const int b = cl >> 1;
      src = ((cl & 1) ? p1 : p0) + (b * NPTS + pt) * 3;
      Lb = Lpred + cl * 65536; Rb = Rpred + cl * 65536;
    } else {
      const int b = cl - NMAT;
      src = gt + (b * NPTS + pt) * 3;
      Lb = Lgt + b * 65536; Rb = Rgt + b * 65536;
    }
    float L[32], R[32];
#pragma unroll
    for (int k = 27; k < 32; ++k){ L[k] = 0.f; R[k] = 0.f; }
#pragma unroll
    for (int c = 0; c < 3; ++c){
      const float v  = src[c];
      const float ah = bfrf(v), al = bfrf(v - ah);
      const float n2 = v * v;
      const float nh = bfrf(n2); const float r1 = n2 - nh;
      const float nm = bfrf(r1); const float nl = bfrf(r1 - nm);
      const int B0 = c * 9;
      L[B0+0]=nh;  L[B0+1]=nm;  L[B0+2]=nl;
      L[B0+3]=1.f; L[B0+4]=1.f; L[B0+5]=1.f;
      L[B0+6]=-2.f*ah; L[B0+7]=-2.f*ah; L[B0+8]=-2.f*al;
      R[B0+0]=1.f; R[B0+1]=1.f; R[B0+2]=1.f;
      R[B0+3]=nh;  R[B0+4]=nm;  R[B0+5]=nl;
      R[B0+6]=ah;  R[B0+7]=al;  R[B0+8]=ah;
    }
    ushort_t Le[32], Re[32];
#pragma unroll
    for (int k = 0; k < 32; ++k){ Le[k] = bfr16(L[k]); Re[k] = bfr16(R[k]); }
    store_enc(Lb, pt, Le);
    store_enc(Rb, pt, Re);
  } else if (idx == totalPts) {
    emd[0] = 0.f;
  } else if (idx == totalPts + 1) {
    chamf[0] = 0.f;
  }
}

// One Sinkhorn half-update over all 32 matrices via MFMA distance tiles.
// Grid = NMAT*32 (XCD-swizzled); block = 512 thr = 8 waves = 4 row-waves x 2 halves.
// Potentials in group-of-4 layout: pot[(t>>2)*64 + c*4 + (t&3)] for point
// index i = t*16+c; lane l loads its 4-tile-group potentials as one float4.
// GSIDE=0: rows=pred (writes FT); GSIDE=1: rows=gt (writes GT).
// RPOT=0: input potentials are zero (very first half-update only).
// COST=1 (final g-update only): also accumulate T_j = sum_i 2^(F_i-K*C)*C,
// then emd += sum_j 2^(G_j) * T_j  (EMD cost fused, no separate pass).
template<int CHAM, int RPOT, int GSIDE, int COST>
__global__ void __launch_bounds__(512, 8) sink_kernel(
    const ushort_t* __restrict__ Lpred, const ushort_t* __restrict__ Rpred,
    const ushort_t* __restrict__ Lgt,   const ushort_t* __restrict__ Rgt,
    float* __restrict__ FT, float* __restrict__ GT,
    float* __restrict__ chamf, float* __restrict__ emd)
{
  // XCD-aware swizzle: give each XCD a contiguous logical range (1024%8==0)
  const int bx0 = blockIdx.x;
  const int bx  = (bx0 & 7) * (NMAT * 32 / 8) + (bx0 >> 3);
  const int m   = bx >> 5;
  const int rg5 = bx & 31;
  const int b   = m >> 1;
  const int tid = threadIdx.x;
  const int l   = tid & 63;
  const int w   = __builtin_amdgcn_readfirstlane(tid >> 6);
  const int wr  = w & 3;
  const int half= w >> 2;

  const ushort_t* A  = GSIDE ? (Lgt + b*65536)   : (Lpred + m*65536);
  const ushort_t* Bm = GSIDE ? (Rpred + m*65536) : (Rgt + b*65536);
  const float* pinT  = (GSIDE ? FT : GT) + m*NPTS;
  float*       poutT = (GSIDE ? GT : FT) + m*NPTS;

  const int myrow16 = rg5*64 + wr*16;

  __shared__ float ssum[8][16];
  __shared__ float sdm[8][16];   // chamfer mins OR cost T sums (never both)
  __shared__ float sds[4];

  const bf16x8 af = *reinterpret_cast<const bf16x8*>(A + (myrow16 >> 4) * 512 + l * 8);

  float s0=0.f,s1=0.f,s2=0.f,s3=0.f;
  float d0=1e30f,d1=1e30f,d2=1e30f,d3=1e30f;
  float t0=0.f,t1=0.f,t2=0.f,t3=0.f;
  const f32x4 zz = {0.f,0.f,0.f,0.f};
  // wave-uniform base (SGPR) + lane offset (VGPR) + immediate tile offsets
  const ushort_t* Bu = Bm + half * (64*512);
  const int voff = l * 8;
  const float* PTu = pinT + (half*16)*64 + (l & 15)*4;

  auto tilef = [&](const bf16x8& bfr, float pv) {
    f32x4 d4 = __builtin_amdgcn_mfma_f32_16x16x32_bf16(af, bfr, zz, 0, 0, 0);
    if (CHAM){
      d0=fminf(d0,d4[0]); d1=fminf(d1,d4[1]);
      d2=fminf(d2,d4[2]); d3=fminf(d3,d4[3]);
    }
    const float Ca=fsqrta(d4[0]), Cb=fsqrta(d4[1]);
    const float Cc=fsqrta(d4[2]), Cd=fsqrta(d4[3]);
    float ea,eb,ec,ed;
    if (RPOT){
      ea=fmaf(-KSCALE,Ca,pv); eb=fmaf(-KSCALE,Cb,pv);
      ec=fmaf(-KSCALE,Cc,pv); ed=fmaf(-KSCALE,Cd,pv);
    } else {
      ea=-KSCALE*Ca; eb=-KSCALE*Cb; ec=-KSCALE*Cc; ed=-KSCALE*Cd;
    }
    const float xa=fexp2(ea), xb=fexp2(eb), xc=fexp2(ec), xd=fexp2(ed);
    s0+=xa; s1+=xb; s2+=xc; s3+=xd;
    if (COST){
      t0=fmaf(xa,Ca,t0); t1=fmaf(xb,Cb,t1);
      t2=fmaf(xc,Cc,t2); t3=fmaf(xd,Cd,t3);
    }
  };

#pragma unroll 4
  for (int g4 = 0; g4 < 16; ++g4) {
    const ushort_t* Bg = Bu + g4 * (4*512);       // uniform (SALU) increment
    float4 cp;
    if (RPOT) cp = *reinterpret_cast<const float4*>(PTu + g4*64);
    else      cp = make_float4(0.f,0.f,0.f,0.f);
    tilef(*reinterpret_cast<const bf16x8*>(Bg + voff + 0*512), cp.x);
    tilef(*reinterpret_cast<const bf16x8*>(Bg + voff + 1*512), cp.y);
    tilef(*reinterpret_cast<const bf16x8*>(Bg + voff + 2*512), cp.z);
    tilef(*reinterpret_cast<const bf16x8*>(Bg + voff + 3*512), cp.w);
  }

  // reduce across the 16 col-lanes of each row
#pragma unroll
  for (int o = 1; o < 16; o <<= 1) {
    s0 += __shfl_xor(s0,o); s1 += __shfl_xor(s1,o);
    s2 += __shfl_xor(s2,o); s3 += __shfl_xor(s3,o);
    if (CHAM){
      d0=fminf(d0,__shfl_xor(d0,o)); d1=fminf(d1,__shfl_xor(d1,o));
      d2=fminf(d2,__shfl_xor(d2,o)); d3=fminf(d3,__shfl_xor(d3,o));
    }
    if (COST){
      t0 += __shfl_xor(t0,o); t1 += __shfl_xor(t1,o);
      t2 += __shfl_xor(t2,o); t3 += __shfl_xor(t3,o);
    }
  }
  if ((l & 15) == 0) {
    const int g = l >> 4;
    ssum[w][g*4+0]=s0; ssum[w][g*4+1]=s1; ssum[w][g*4+2]=s2; ssum[w][g*4+3]=s3;
    if (CHAM){ sdm[w][g*4+0]=d0; sdm[w][g*4+1]=d1; sdm[w][g*4+2]=d2; sdm[w][g*4+3]=d3; }
    if (COST){ sdm[w][g*4+0]=t0; sdm[w][g*4+1]=t1; sdm[w][g*4+2]=t2; sdm[w][g*4+3]=t3; }
  }
  __syncthreads();
  float val = 0.f;
  if (w < 4 && l < 16) {
    const float S = ssum[w][l] + ssum[w+4][l];
    val = -11.0f - flog2(S);
    // row grow = rg5*64 + w*16 + l -> group rg5, tile-in-group w, col l
    poutT[rg5*64 + l*4 + w] = val;   // dense 256B per block
  }
  if (CHAM) {
    if (w < 4) {
      float dmr = (l < 16) ? fminf(sdm[w][l], sdm[w+4][l]) : 0.f;
#pragma unroll
      for (int o = 1; o < 16; o <<= 1) dmr += __shfl_xor(dmr, o);
      if (l == 0) sds[w] = dmr;
    }
    __syncthreads();
    if (tid == 0) atomicAdd(chamf, (sds[0]+sds[1])+(sds[2]+sds[3]));
  }
  if (COST) {
    if (w < 4) {
      float cj = (l < 16) ? fexp2(val) * (sdm[w][l] + sdm[w+4][l]) : 0.f;
#pragma unroll
      for (int o = 1; o < 16; o <<= 1) cj += __shfl_xor(cj, o);
      if (l == 0) sds[w] = cj;
    }
    __syncthreads();
    if (tid == 0) atomicAdd(emd, (sds[0]+sds[1])+(sds[2]+sds[3]));
  }
}

__global__ void final_kernel(const float* __restrict__ emd,
                             const float* __restrict__ chamf,
                             float* __restrict__ out)
{
  if (blockIdx.x == 0 && threadIdx.x == 0) {
    out[0] = chamf[0] / (float)(BATCH * NPTS) + emd[0] / (float)BATCH;
  }
}

extern "C" void kernel_launch(void* const* d_in, const int* in_sizes, int n_in,
                              void* d_out, int out_size, void* d_ws, size_t ws_size,
                              hipStream_t stream) {
  (void)in_sizes; (void)n_in; (void)out_size; (void)ws_size;
  const float* gt = (const float*)d_in[0];
  const float* p0 = (const float*)d_in[2];
  const float* p1 = (const float*)d_in[3];

  ushort_t* Lpred = (ushort_t*)d_ws;                  // 4MB
  ushort_t* Rpred = Lpred + NMAT * 65536;             // 4MB
  ushort_t* Lgt   = Rpred + NMAT * 65536;             // 2MB
  ushort_t* Rgt   = Lgt + BATCH * 65536;              // 2MB
  float* FT    = (float*)(Rgt + BATCH * 65536);       // 32*2048 (grouped-T)
  float* GT    = FT + NMAT * NPTS;                    // 32*2048 (grouped-T)
  float* emd   = GT + NMAT * NPTS;                    // 1
  float* chamf = emd + 1;                             // 1

  const int initN = (NMAT + BATCH) * NPTS + 2;
  pack_kernel<<<(initN + 255) / 256, 256, 0, stream>>>(
      gt, p0, p1, Lpred, Rpred, Lgt, Rgt, emd, chamf);

  const int grid = NMAT * 32;   // 1024 blocks, 8 waves each, 64 rows/block
  sink_kernel<1, 0, 0, 0><<<grid, 512, 0, stream>>>(Lpred, Rpred, Lgt, Rgt, FT, GT, chamf, emd);
  sink_kernel<1, 1, 1, 0><<<grid, 512, 0, stream>>>(Lpred, Rpred, Lgt, Rgt, FT, GT, chamf, emd);
  for (int it = 1; it < ITERS - 1; ++it) {
    sink_kernel<0, 1, 0, 0><<<grid, 512, 0, stream>>>(Lpred, Rpred, Lgt, Rgt, FT, GT, chamf, emd);
    sink_kernel<0, 1, 1, 0><<<grid, 512, 0, stream>>>(Lpred, Rpred, Lgt, Rgt, FT, GT, chamf, emd);
  }
  // final iteration: f-update, then g-update with fused EMD cost
  sink_kernel<0, 1, 0, 0><<<grid, 512, 0, stream>>>(Lpred, Rpred, Lgt, Rgt, FT, GT, chamf, emd);
  sink_kernel<0, 1, 1, 1><<<grid, 512, 0, stream>>>(Lpred, Rpred, Lgt, Rgt, FT, GT, chamf, emd);
  final_kernel<<<1, 64, 0, stream>>>(emd, chamf, (float*)d_out);
}